// Round 4
// baseline (1467.788 us; speedup 1.0000x reference)
//
#include <hip/hip_runtime.h>
#include <hip/hip_bf16.h>

using bf16 = __hip_bfloat16;
typedef __attribute__((ext_vector_type(8))) short bf16x8_t;   // 8 bf16 = 4 VGPR (MFMA A/B frag)
typedef __attribute__((ext_vector_type(4))) float f32x4_t;    // MFMA C/D frag

#define DEVI __device__ __forceinline__

constexpr int kB = 2, kC = 2048, kS = 1024, kH = 16, kHD = 128, kFF = 8192;
constexpr int kNT = kB * kS;                 // 2048 token-columns (n = b*S + s)
constexpr float kEPS = 1e-5f;
constexpr float kSCALE = 0.08838834764831845f;   // 1/sqrt(128)

DEVI void gload16(const bf16* g, bf16* l) {
  __builtin_amdgcn_global_load_lds(
      (const __attribute__((address_space(1))) unsigned int*)g,
      (__attribute__((address_space(3))) unsigned int*)l, 16, 0, 0);
}

// ---------------- small utility kernels ----------------

// fp32 -> bf16 linear convert (n elements, n % 1024 == 0), grid = n/1024
__global__ void f32_to_bf16_k(const float* __restrict__ src, bf16* __restrict__ dst) {
  size_t i = ((size_t)blockIdx.x * 256 + threadIdx.x) * 4;
  float4 v = *(const float4*)(src + i);
  dst[i + 0] = __float2bfloat16(v.x);
  dst[i + 1] = __float2bfloat16(v.y);
  dst[i + 2] = __float2bfloat16(v.z);
  dst[i + 3] = __float2bfloat16(v.w);
}

// v_cache (B,H,HD,S) f32 -> Vbuf (rows o=h*HD+d, cols n=b*S+s) bf16
__global__ void vcache_init_k(const float* __restrict__ vc, bf16* __restrict__ vbuf) {
  size_t i = ((size_t)blockIdx.x * 256 + threadIdx.x) * 4;
  int s = (int)(i & (kS - 1));
  int d = (int)((i >> 10) & (kHD - 1));
  int h = (int)((i >> 17) & (kH - 1));
  int b = (int)(i >> 21);
  float4 v = *(const float4*)(vc + i);
  bf16* dst = vbuf + (size_t)(h * kHD + d) * kNT + b * kS + s;
  dst[0] = __float2bfloat16(v.x);
  dst[1] = __float2bfloat16(v.y);
  dst[2] = __float2bfloat16(v.z);
  dst[3] = __float2bfloat16(v.w);
}

// 1024x1024 f32 transpose (mask (k,q) -> (q,k)), grid (32,32), block 256
__global__ void transpose_f32_k(const float* __restrict__ in, float* __restrict__ out) {
  __shared__ float tl[32][33];
  int c0 = blockIdx.x * 32, r0 = blockIdx.y * 32;
  int t = threadIdx.x, cl = t & 31, ri = t >> 5;
#pragma unroll
  for (int k = 0; k < 4; ++k)
    tl[ri + 8 * k][cl] = in[(size_t)(r0 + ri + 8 * k) * kS + c0 + cl];
  __syncthreads();
#pragma unroll
  for (int k = 0; k < 4; ++k)
    out[(size_t)(c0 + ri + 8 * k) * kS + r0 + cl] = tl[cl][ri + 8 * k];
}

// g = silu(g)*u elementwise bf16, grid = n/1024
__global__ void silu_mul_k(bf16* __restrict__ g, const bf16* __restrict__ u) {
  size_t i = ((size_t)blockIdx.x * 256 + threadIdx.x) * 4;
  short4 gs = *(const short4*)(g + i);
  short4 us = *(const short4*)(u + i);
  short4 ov;
#pragma unroll
  for (int j = 0; j < 4; ++j) {
    float gf = __bfloat162float(((const bf16*)&gs)[j]);
    float uf = __bfloat162float(((const bf16*)&us)[j]);
    float sg = gf / (1.0f + __expf(-gf));
    ((bf16*)&ov)[j] = __float2bfloat16(sg * uf);
  }
  *(short4*)(g + i) = ov;
}

// ---------------- RMSNorm (over channel dim) + transpose ----------------

// partial sums of x^2 over c-chunks: grid (kNT/256, 16)
__global__ void rms_part_k(const float* __restrict__ x, float* __restrict__ part) {
  int n = blockIdx.x * 256 + threadIdx.x;     // token column 0..2047
  int cg = blockIdx.y;                        // 16 chunks of 128 channels
  int b = n >> 10, s = n & (kS - 1);
  const float* px = x + (size_t)b * kC * kS + s;
  float acc = 0.f;
#pragma unroll 4
  for (int c = cg * 128; c < cg * 128 + 128; ++c) {
    float v = px[(size_t)c * kS];
    acc += v * v;
  }
  part[cg * kNT + n] = acc;
}

// normalize + write transposed Xn_t[n][c] bf16; grid (kC/32, kNT/32), block 256
__global__ void rmsnorm_t_k(const float* __restrict__ x, const float* __restrict__ part,
                            const float* __restrict__ w, bf16* __restrict__ xt) {
  __shared__ float tile[32][33];
  __shared__ float sinv[32];
  __shared__ float sw[32];
  int t = threadIdx.x;
  int c0 = blockIdx.x * 32, n0 = blockIdx.y * 32;
  if (t < 32) {
    float sum = 0.f;
#pragma unroll
    for (int g = 0; g < 16; ++g) sum += part[g * kNT + n0 + t];
    sinv[t] = rsqrtf(sum * (1.0f / kC) + kEPS);
  } else if (t < 64) {
    sw[t - 32] = w[c0 + t - 32];
  }
  __syncthreads();
  int nl = t & 31, ci = t >> 5;
  int nn = n0 + nl;
  int b = nn >> 10, s = nn & (kS - 1);
#pragma unroll
  for (int k = 0; k < 4; ++k) {
    int c = ci + 8 * k;
    float v = x[(size_t)b * kC * kS + (size_t)(c0 + c) * kS + s];
    tile[c][nl] = v * sinv[nl] * sw[c];
  }
  __syncthreads();
  int cl = t & 31, ni = t >> 5;
#pragma unroll
  for (int k = 0; k < 4; ++k) {
    int n = ni + 8 * k;
    xt[(size_t)(n0 + n) * kC + c0 + cl] = __float2bfloat16(tile[cl][n]);
  }
}

// ---------------- RoPE (rotate-half) + transpose to (B,H,S,HD) ----------------
// in: P rows o=h*HD+d, cols n=b*S+s (bf16). out: outT[((b*H+h)*S + srow)*HD + d]
// srow = idx ? idx[s] : s   (KV-cache scatter). grid (S/32, B*H), block 256.
__global__ void rope_t_k(const bf16* __restrict__ P, const float* __restrict__ sintab,
                         const float* __restrict__ costab, bf16* __restrict__ outT,
                         const int* __restrict__ idx) {
  __shared__ float raw[128][33];
  __shared__ float ssin[64][33];
  __shared__ float scos[64][33];
  const int bh = blockIdx.y, b = bh >> 4, h = bh & 15;
  const int s0 = blockIdx.x * 32;
  const int t = threadIdx.x, sl = t & 31, di = t >> 5;
#pragma unroll
  for (int k = 0; k < 16; ++k) {
    int d = di + 8 * k;
    raw[d][sl] = __bfloat162float(P[(size_t)(h * kHD + d) * kNT + b * kS + s0 + sl]);
  }
#pragma unroll
  for (int k = 0; k < 8; ++k) {
    int d = di + 8 * k;   // sin/cos rows 64..127 duplicate 0..63
    ssin[d][sl] = sintab[(size_t)d * kS + s0 + sl];
    scos[d][sl] = costab[(size_t)d * kS + s0 + sl];
  }
  __syncthreads();
  const int dl = t & 127, si = t >> 7;
  const int dr = dl & 63;
#pragma unroll
  for (int k = 0; k < 16; ++k) {
    int sL = si + 2 * k;
    float v = raw[dl][sL];
    float partner = raw[dl ^ 64][sL];
    float sn = ssin[dr][sL], cs = scos[dr][sL];
    float o = v * cs + ((dl < 64) ? -partner : partner) * sn;
    int srow = s0 + sL;
    if (idx) srow = idx[srow];
    outT[((size_t)bh * kS + srow) * kHD + dl] = __float2bfloat16(o);
  }
}

// ---------------- softmax over k (rows of scoresT), in-place bf16 ----------------
// grid = B*H*S blocks, block 256. scoresT[(bh*S+q)*S + k] (already scaled).
__global__ void softmax_k(bf16* __restrict__ sc, const float* __restrict__ maskT) {
  const int r = blockIdx.x;
  const int q = r & (kS - 1);
  bf16* row = sc + (size_t)r * kS;
  const float* mrow = maskT + (size_t)q * kS;
  const int t = threadIdx.x;
  short4 sv = *(const short4*)(row + t * 4);
  float4 mv = *(const float4*)(mrow + t * 4);
  float v[4];
  v[0] = __bfloat162float(((const bf16*)&sv)[0]) + mv.x;
  v[1] = __bfloat162float(((const bf16*)&sv)[1]) + mv.y;
  v[2] = __bfloat162float(((const bf16*)&sv)[2]) + mv.z;
  v[3] = __bfloat162float(((const bf16*)&sv)[3]) + mv.w;
  float mx = fmaxf(fmaxf(v[0], v[1]), fmaxf(v[2], v[3]));
#pragma unroll
  for (int o = 1; o < 64; o <<= 1) mx = fmaxf(mx, __shfl_xor(mx, o));
  __shared__ float red[4];
  __shared__ float red2[4];
  if ((t & 63) == 0) red[t >> 6] = mx;
  __syncthreads();
  mx = fmaxf(fmaxf(red[0], red[1]), fmaxf(red[2], red[3]));
  float sum = 0.f;
#pragma unroll
  for (int j = 0; j < 4; ++j) { v[j] = __expf(v[j] - mx); sum += v[j]; }
#pragma unroll
  for (int o = 1; o < 64; o <<= 1) sum += __shfl_xor(sum, o);
  if ((t & 63) == 0) red2[t >> 6] = sum;
  __syncthreads();
  sum = red2[0] + red2[1] + red2[2] + red2[3];
  float inv = 1.0f / sum;
  short4 ov;
#pragma unroll
  for (int j = 0; j < 4; ++j) ((bf16*)&ov)[j] = __float2bfloat16(v[j] * inv);
  *(short4*)(row + t * 4) = ov;
}

// ---------------- bf16 MFMA GEMM: C[M,N] = A[M,K] * B[N,K]^T ----------------
// m97 structure: 128x128 tile, BK=32, 4 waves (2x2 of 64x64), global_load_lds x16B.
// Batched via blockIdx.z decomposed as (bb = z>>4, hh = z&15) with separate strides.
struct GemmP {
  const bf16* A; const bf16* B;
  long sAb, sAh, sBb, sBh;
  int lda, ldb, K;
  bf16* C; long sCb, sCh; int ldc;
  float scale;
  const float* resid; float* fout;    // EPI 2
  const int* colmap;                  // EPI 3
};

// EPI: 0 = bf16 C (scaled); 1 = bf16 C^T; 2 = f32 out[b,c,s] = resid + acc;
//      3 = bf16 C with column scatter (col -> b*S + colmap[s])
template <int EPI>
__global__ void __launch_bounds__(256) gemm_bt(GemmP p) {
  constexpr int BK = 32;
  __shared__ alignas(16) bf16 As[128 * BK];
  __shared__ alignas(16) bf16 Bs[128 * BK];
  const int bz = blockIdx.z, bb = bz >> 4, hh = bz & 15;
  const bf16* Ab = p.A + (size_t)bb * p.sAb + (size_t)hh * p.sAh;
  const bf16* Bb = p.B + (size_t)bb * p.sBb + (size_t)hh * p.sBh;
  const int m0 = blockIdx.x * 128, n0 = blockIdx.y * 128;
  const int t = threadIdx.x, lane = t & 63;
  const int w = t >> 6, wm = (w >> 1) << 6, wn = (w & 1) << 6;
  const int sr = t >> 2, scol = (t & 3) << 3;
  const bf16* ga0 = Ab + (size_t)(m0 + sr) * p.lda + scol;
  const bf16* ga1 = ga0 + (size_t)64 * p.lda;
  const bf16* gb0 = Bb + (size_t)(n0 + sr) * p.ldb + scol;
  const bf16* gb1 = gb0 + (size_t)64 * p.ldb;
  bf16* la0 = As + t * 8;
  bf16* la1 = As + 2048 + t * 8;
  bf16* lb0 = Bs + t * 8;
  bf16* lb1 = Bs + 2048 + t * 8;
  const int fr = lane & 15, fq = lane >> 4;
  f32x4_t acc[4][4] = {};
  const int KTn = p.K / BK;
  for (int kt = 0; kt < KTn; ++kt) {
    const int kk = kt * BK;
    gload16(ga0 + kk, la0);
    gload16(ga1 + kk, la1);
    gload16(gb0 + kk, lb0);
    gload16(gb1 + kk, lb1);
    __syncthreads();
    bf16x8_t av[4], bv[4];
#pragma unroll
    for (int m = 0; m < 4; ++m)
      av[m] = *(const bf16x8_t*)&As[(wm + m * 16 + fr) * BK + fq * 8];
#pragma unroll
    for (int n = 0; n < 4; ++n)
      bv[n] = *(const bf16x8_t*)&Bs[(wn + n * 16 + fr) * BK + fq * 8];
#pragma unroll
    for (int m = 0; m < 4; ++m)
#pragma unroll
      for (int n = 0; n < 4; ++n)
        acc[m][n] = __builtin_amdgcn_mfma_f32_16x16x32_bf16(av[m], bv[n], acc[m][n], 0, 0, 0);
    __syncthreads();
  }
  bf16* cb = p.C + (size_t)bb * p.sCb + (size_t)hh * p.sCh;
#pragma unroll
  for (int m = 0; m < 4; ++m) {
#pragma unroll
    for (int n = 0; n < 4; ++n) {
      const f32x4_t v = acc[m][n];
      const int row0 = m0 + wm + m * 16 + fq * 4;
      const int col = n0 + wn + n * 16 + fr;
      if constexpr (EPI == 0) {
#pragma unroll
        for (int j = 0; j < 4; ++j)
          cb[(size_t)(row0 + j) * p.ldc + col] = __float2bfloat16(v[j] * p.scale);
      } else if constexpr (EPI == 1) {
#pragma unroll
        for (int j = 0; j < 4; ++j)
          cb[(size_t)col * p.ldc + row0 + j] = __float2bfloat16(v[j]);
      } else if constexpr (EPI == 2) {
        const int b = col >> 10, s = col & (kS - 1);
#pragma unroll
        for (int j = 0; j < 4; ++j) {
          const size_t a = (size_t)b * kC * kS + (size_t)(row0 + j) * kS + s;
          p.fout[a] = p.resid[a] + v[j];
        }
      } else {  // EPI == 3: V-projection with KV-cache column scatter
        const int bcol = col >> 10, s = col & (kS - 1);
        const int dc = bcol * kS + p.colmap[s];
#pragma unroll
        for (int j = 0; j < 4; ++j)
          cb[(size_t)(row0 + j) * p.ldc + dc] = __float2bfloat16(v[j]);
      }
    }
  }
}

// ---------------- host ----------------

extern "C" void kernel_launch(void* const* d_in, const int* in_sizes, int n_in,
                              void* d_out, int out_size, void* d_ws, size_t ws_size,
                              hipStream_t stream) {
  (void)in_sizes; (void)n_in; (void)out_size; (void)ws_size;
  const float* x      = (const float*)d_in[0];
  const float* sin_q  = (const float*)d_in[1];
  const float* cos_q  = (const float*)d_in[2];
  const float* sin_k  = (const float*)d_in[3];
  const float* cos_k  = (const float*)d_in[4];
  const int*   kv_idx = (const int*)d_in[5];
  const float* mask_s = (const float*)d_in[7];
  const float* mask_c = (const float*)d_in[8];
  const float* kcache = (const float*)d_in[9];
  const float* vcache = (const float*)d_in[10];
  const float* w_sa   = (const float*)d_in[11];
  const float* wq_sa  = (const float*)d_in[12];
  const float* wk_sa  = (const float*)d_in[13];
  const float* wv_sa  = (const float*)d_in[14];
  const float* wo_sa  = (const float*)d_in[15];
  const float* w_ca   = (const float*)d_in[16];
  const float* wq_ca  = (const float*)d_in[17];
  const float* wk_ca  = (const float*)d_in[18];
  const float* wv_ca  = (const float*)d_in[19];
  const float* wo_ca  = (const float*)d_in[20];
  const float* w_mlp  = (const float*)d_in[21];
  const float* w_gate = (const float*)d_in[22];
  const float* w_up   = (const float*)d_in[23];
  const float* w_down = (const float*)d_in[24];
  float* out = (float*)d_out;

  const size_t WA = (size_t)kC * kC;    // 4.19M elems
  const size_t WF = (size_t)kFF * kC;   // 16.78M elems

  char* W = (char*)d_ws;
  size_t off = 0;
  auto take = [&](size_t bytes) {
    char* p = W + off;
    off = (off + bytes + 255) & ~(size_t)255;
    return p;
  };
  // Weight staging buffer: shared across phases (converted per-phase, stream-ordered).
  // Sized for the MLP phase (3 x WF bf16 = 100.7 MB); attention phases use the
  // first 4 x WA bf16 = 33.6 MB of it. Peak total ws use ~235 MB.
  bf16* WB = (bf16*)take(3 * WF * 2);
  bf16* w0 = WB;            // wq  | w_gate
  bf16* w1 = WB + WA;       // wk
  bf16* w2 = WB + 2 * WA;   // wv
  bf16* w3 = WB + 3 * WA;   // wo
  bf16* wgB = WB;           // MLP: gate
  bf16* wuB = WB + WF;      // MLP: up
  bf16* wdB = WB + 2 * WF;  // MLP: down
  float* maskTs = (float*)take((size_t)kS * kS * 4);
  float* maskTc = (float*)take((size_t)kS * kS * 4);
  float* partial = (float*)take((size_t)16 * kNT * 4);
  bf16* XnT = (bf16*)take((size_t)kNT * kC * 2);
  bf16* QT = (bf16*)take(WA * 2);
  bf16* KTb = (bf16*)take(WA * 2);
  bf16* Vbuf = (bf16*)take(WA * 2);
  bf16* attnT = (bf16*)take(WA * 2);
  float* xcur = (float*)take((size_t)kB * kC * kS * 4);
  char* R1 = take((size_t)kB * kH * kS * kS * 2);  // 67 MB, lifetime-shared
  bf16* Qb = (bf16*)R1;                       // dead before scores written
  bf16* Kb = (bf16*)(R1 + WA * 2);
  bf16* scores = (bf16*)R1;                   // attn phase
  bf16* gateT = (bf16*)R1;                    // mlp phase: [kNT][kFF] = 33.55 MB
  bf16* upT = (bf16*)(R1 + (size_t)kNT * kFF * 2);  // R1 + 33.55 MB (no overlap)

  auto cvt = [&](const float* s, bf16* d, size_t n) {
    f32_to_bf16_k<<<dim3((unsigned)(n / 1024)), 256, 0, stream>>>(s, d);
  };
  transpose_f32_k<<<dim3(32, 32), 256, 0, stream>>>(mask_s, maskTs);
  transpose_f32_k<<<dim3(32, 32), 256, 0, stream>>>(mask_c, maskTc);

  auto proj = [&](const bf16* Wm, bf16* Cdst) {
    GemmP p{};
    p.A = Wm; p.B = XnT; p.lda = kC; p.ldb = kC; p.K = kC;
    p.C = Cdst; p.ldc = kNT; p.scale = 1.0f;
    gemm_bt<0><<<dim3(16, 16, 1), 256, 0, stream>>>(p);
  };

  auto attn = [&](const float* xin, const float* resid, const float* wnorm,
                  const float* wq_f, const float* wk_f, const float* wv_f,
                  const float* wo_f, const float* maskT, bool cache) {
    // convert this block's weights into the shared staging buffer
    cvt(wq_f, w0, WA); cvt(wk_f, w1, WA); cvt(wv_f, w2, WA); cvt(wo_f, w3, WA);
    rms_part_k<<<dim3(kNT / 256, 16), 256, 0, stream>>>(xin, partial);
    rmsnorm_t_k<<<dim3(kC / 32, kNT / 32), 256, 0, stream>>>(xin, partial, wnorm, XnT);
    proj(w0, Qb);
    proj(w1, Kb);
    if (cache) {
      f32_to_bf16_k<<<dim3((unsigned)(WA / 1024)), 256, 0, stream>>>(kcache, KTb);
      vcache_init_k<<<dim3((unsigned)(WA / 1024)), 256, 0, stream>>>(vcache, Vbuf);
      GemmP pv{};
      pv.A = w2; pv.B = XnT; pv.lda = kC; pv.ldb = kC; pv.K = kC;
      pv.C = Vbuf; pv.ldc = kNT; pv.scale = 1.0f; pv.colmap = kv_idx;
      gemm_bt<3><<<dim3(16, 16, 1), 256, 0, stream>>>(pv);
    } else {
      proj(w2, Vbuf);
    }
    rope_t_k<<<dim3(32, 32), 256, 0, stream>>>(Qb, sin_q, cos_q, QT, nullptr);
    rope_t_k<<<dim3(32, 32), 256, 0, stream>>>(Kb, sin_k, cos_k, KTb, cache ? kv_idx : nullptr);
    // scoresT[q][k] = SCALE * sum_d Q_t[q][d] * K_t[k][d], batched over (b,h)
    GemmP qk{};
    qk.A = QT; qk.B = KTb; qk.lda = kHD; qk.ldb = kHD; qk.K = kHD;
    qk.sAb = (long)kH * kS * kHD; qk.sAh = (long)kS * kHD;
    qk.sBb = qk.sAb; qk.sBh = qk.sAh;
    qk.C = scores; qk.ldc = kS; qk.sCb = (long)kH * kS * kS; qk.sCh = (long)kS * kS;
    qk.scale = kSCALE;
    gemm_bt<0><<<dim3(8, 8, 32), 256, 0, stream>>>(qk);
    softmax_k<<<dim3(kB * kH * kS), 256, 0, stream>>>(scores, maskT);
    // out[d][q] = sum_k V[d][k] * P_t[q][k]; write transposed into attnT[n][h*HD+d]
    GemmP pvg{};
    pvg.A = Vbuf; pvg.lda = kNT; pvg.sAb = kS; pvg.sAh = (long)kHD * kNT;
    pvg.B = scores; pvg.ldb = kS; pvg.sBb = (long)kH * kS * kS; pvg.sBh = (long)kS * kS;
    pvg.K = kS;
    pvg.C = attnT; pvg.ldc = kC; pvg.sCb = (long)kS * kC; pvg.sCh = kHD;
    gemm_bt<1><<<dim3(1, 8, 32), 256, 0, stream>>>(pvg);
    // output projection + residual (f32)
    GemmP po{};
    po.A = w3; po.B = attnT; po.lda = kC; po.ldb = kC; po.K = kC;
    po.resid = resid; po.fout = xcur;
    gemm_bt<2><<<dim3(16, 16, 1), 256, 0, stream>>>(po);
  };

  // self-attention block (residual = original x)
  attn(x, x, w_sa, wq_sa, wk_sa, wv_sa, wo_sa, maskTs, true);
  // cross-attention block (Xq = Xkv = xcur, residual = xcur, no cache)
  attn(xcur, xcur, w_ca, wq_ca, wk_ca, wv_ca, wo_ca, maskTc, false);

  // MLP block
  cvt(w_gate, wgB, WF); cvt(w_up, wuB, WF); cvt(w_down, wdB, WF);
  rms_part_k<<<dim3(kNT / 256, 16), 256, 0, stream>>>(xcur, partial);
  rmsnorm_t_k<<<dim3(kC / 32, kNT / 32), 256, 0, stream>>>(xcur, partial, w_mlp, XnT);
  {
    GemmP gg{};
    gg.A = wgB; gg.B = XnT; gg.lda = kC; gg.ldb = kC; gg.K = kC;
    gg.C = gateT; gg.ldc = kFF;
    gemm_bt<1><<<dim3(kFF / 128, kNT / 128, 1), 256, 0, stream>>>(gg);
    GemmP gu{};
    gu.A = wuB; gu.B = XnT; gu.lda = kC; gu.ldb = kC; gu.K = kC;
    gu.C = upT; gu.ldc = kFF;
    gemm_bt<1><<<dim3(kFF / 128, kNT / 128, 1), 256, 0, stream>>>(gu);
    silu_mul_k<<<dim3((unsigned)(((size_t)kNT * kFF) / 1024)), 256, 0, stream>>>(gateT, upT);
    GemmP gd{};
    gd.A = wdB; gd.B = gateT; gd.lda = kFF; gd.ldb = kFF; gd.K = kFF;
    gd.resid = xcur; gd.fout = out;
    gemm_bt<2><<<dim3(16, 16, 1), 256, 0, stream>>>(gd);
  }
}